// Round 1
// baseline (550.439 us; speedup 1.0000x reference)
//
#include <hip/hip_runtime.h>
#include <hip/hip_bf16.h>
#include <stdint.h>

#define D_DIM 2048
#define B_DIM 1024
#define N_TOT 3072
#define NCLS 64
#define MARGIN_F 0.8f
#define BIG_F 1e30f
#define LDT 40   // LDS row stride (elements) for GEMM tiles: 80B rows -> <=2-way bank aliasing, 16B aligned

typedef float f32x4 __attribute__((ext_vector_type(4)));
typedef __bf16 bf16x8 __attribute__((ext_vector_type(8)));

// ---------------- block reduction helpers ----------------
__device__ inline float block_reduce_sum(float v, float* sred) {
    int tid = threadIdx.x;
    sred[tid] = v; __syncthreads();
    for (int s = 128; s > 0; s >>= 1) {
        if (tid < s) sred[tid] = sred[tid] + sred[tid + s];
        __syncthreads();
    }
    float r = sred[0]; __syncthreads();
    return r;
}
__device__ inline float block_reduce_max(float v, float* sred) {
    int tid = threadIdx.x;
    sred[tid] = v; __syncthreads();
    for (int s = 128; s > 0; s >>= 1) {
        if (tid < s) sred[tid] = fmaxf(sred[tid], sred[tid + s]);
        __syncthreads();
    }
    float r = sred[0]; __syncthreads();
    return r;
}
__device__ inline float block_reduce_min(float v, float* sred) {
    int tid = threadIdx.x;
    sred[tid] = v; __syncthreads();
    for (int s = 128; s > 0; s >>= 1) {
        if (tid < s) sred[tid] = fminf(sred[tid], sred[tid + s]);
        __syncthreads();
    }
    float r = sred[0]; __syncthreads();
    return r;
}

__device__ inline int label_of(int j, const int* __restrict__ albl, const int* __restrict__ nlbl) {
    return (j < 2 * B_DIM) ? albl[j & (B_DIM - 1)] : nlbl[j - 2 * B_DIM];
}

// ---------------- 0: zero accumulators ----------------
__global__ __launch_bounds__(256) void zero_kernel(float* __restrict__ T, float* __restrict__ scal) {
    int t = blockIdx.x * 256 + threadIdx.x;
    if (t < NCLS * NCLS) T[t] = 0.f;
    if (t < 8) scal[t] = 0.f;
}

// ---------------- 1: fp32 -> bf16 embed matrix + exact fp32 row norms ----------------
__global__ __launch_bounds__(256) void convert_norms_kernel(
        const float* __restrict__ A, const float* __restrict__ P, const float* __restrict__ Ng,
        __bf16* __restrict__ Eb, float* __restrict__ norms) {
    __shared__ float sred[256];
    int i = blockIdx.x;
    int tid = threadIdx.x;
    const float* src = (i < B_DIM) ? (A + (size_t)i * D_DIM)
                     : (i < 2 * B_DIM) ? (P + (size_t)(i - B_DIM) * D_DIM)
                     : (Ng + (size_t)(i - 2 * B_DIM) * D_DIM);
    const f32x4* s4 = (const f32x4*)src;
    f32x4 v0 = s4[tid * 2];
    f32x4 v1 = s4[tid * 2 + 1];
    float ss = v0[0]*v0[0] + v0[1]*v0[1] + v0[2]*v0[2] + v0[3]*v0[3]
             + v1[0]*v1[0] + v1[1]*v1[1] + v1[2]*v1[2] + v1[3]*v1[3];
    float vals[8] = {v0[0], v0[1], v0[2], v0[3], v1[0], v1[1], v1[2], v1[3]};
    bf16x8 o;
    #pragma unroll
    for (int e = 0; e < 8; ++e) o[e] = (__bf16)vals[e];
    *(bf16x8*)(Eb + (size_t)i * D_DIM + tid * 8) = o;
    float tot = block_reduce_sum(ss, sred);
    if (tid == 0) norms[i] = tot;
}

// ---------------- 2: exact fp32 triplet term ----------------
__global__ __launch_bounds__(256) void triplet_kernel(
        const float* __restrict__ A, const float* __restrict__ P, const float* __restrict__ Ng,
        float* __restrict__ scal) {
    __shared__ float sred[256];
    int i = blockIdx.x, tid = threadIdx.x;
    const f32x4* a4 = (const f32x4*)(A + (size_t)i * D_DIM);
    const f32x4* p4 = (const f32x4*)(P + (size_t)i * D_DIM);
    const f32x4* n4 = (const f32x4*)(Ng + (size_t)i * D_DIM);
    float pd = 0.f, nd = 0.f;
    for (int k = tid; k < D_DIM / 4; k += 256) {
        f32x4 av = a4[k], pv = p4[k], nv = n4[k];
        f32x4 dp = av - pv, dn = av - nv;
        pd += dp[0]*dp[0] + dp[1]*dp[1] + dp[2]*dp[2] + dp[3]*dp[3];
        nd += dn[0]*dn[0] + dn[1]*dn[1] + dn[2]*dn[2] + dn[3]*dn[3];
    }
    float pall = block_reduce_sum(pd, sred);
    float nall = block_reduce_sum(nd, sred);
    if (tid == 0) atomicAdd(&scal[0], fmaxf(pall - nall + MARGIN_F, 0.f));
}

// ---------------- 3: bf16 MFMA Gram: G = E * E^T  (128x128 tile, 4 waves, reg-staged LDS) ----------------
__global__ __launch_bounds__(256) void gram_gemm(const __bf16* __restrict__ Eb, float* __restrict__ G) {
    __shared__ __bf16 As[128 * LDT] __attribute__((aligned(16)));
    __shared__ __bf16 Bs[128 * LDT] __attribute__((aligned(16)));
    int tid = threadIdx.x;
    int lane = tid & 63, wave = tid >> 6;
    int bx = blockIdx.x % (N_TOT / 128);
    int by = blockIdx.x / (N_TOT / 128);
    size_t row0 = (size_t)by * 128, col0 = (size_t)bx * 128;
    int wr = wave >> 1, wc = wave & 1;          // wave -> 64x64 quadrant
    const f32x4 z4 = {0.f, 0.f, 0.f, 0.f};
    f32x4 acc[4][4];
    #pragma unroll
    for (int m = 0; m < 4; ++m)
        #pragma unroll
        for (int n = 0; n < 4; ++n) acc[m][n] = z4;

    int r_a = tid >> 2;          // staging row within [0,64)
    int c_a = (tid & 3) * 8;     // staging col 0/8/16/24
    const __bf16* arow = Eb + row0 * D_DIM;
    const __bf16* brow = Eb + col0 * D_DIM;
    int rl = lane & 15;
    int kg = (lane >> 4) * 8;    // k-offset of this lane's fragment

    for (int k0 = 0; k0 < D_DIM; k0 += 32) {
        bf16x8 a0 = *(const bf16x8*)(arow + (size_t)r_a * D_DIM + k0 + c_a);
        bf16x8 a1 = *(const bf16x8*)(arow + (size_t)(r_a + 64) * D_DIM + k0 + c_a);
        bf16x8 b0 = *(const bf16x8*)(brow + (size_t)r_a * D_DIM + k0 + c_a);
        bf16x8 b1 = *(const bf16x8*)(brow + (size_t)(r_a + 64) * D_DIM + k0 + c_a);
        __syncthreads();   // previous iteration's LDS reads done before overwrite
        *(bf16x8*)&As[r_a * LDT + c_a] = a0;
        *(bf16x8*)&As[(r_a + 64) * LDT + c_a] = a1;
        *(bf16x8*)&Bs[r_a * LDT + c_a] = b0;
        *(bf16x8*)&Bs[(r_a + 64) * LDT + c_a] = b1;
        __syncthreads();
        bf16x8 af[4], bf[4];
        #pragma unroll
        for (int m = 0; m < 4; ++m)
            af[m] = *(const bf16x8*)&As[(wr * 64 + m * 16 + rl) * LDT + kg];
        #pragma unroll
        for (int n = 0; n < 4; ++n)
            bf[n] = *(const bf16x8*)&Bs[(wc * 64 + n * 16 + rl) * LDT + kg];
        #pragma unroll
        for (int m = 0; m < 4; ++m)
            #pragma unroll
            for (int n = 0; n < 4; ++n)
                acc[m][n] = __builtin_amdgcn_mfma_f32_16x16x32_bf16(af[m], bf[n], acc[m][n], 0, 0, 0);
    }
    // C/D layout (HW-verified): col = lane&15, row = (lane>>4)*4 + reg
    int rg = (lane >> 4) * 4;
    #pragma unroll
    for (int m = 0; m < 4; ++m)
        #pragma unroll
        for (int n = 0; n < 4; ++n)
            #pragma unroll
            for (int r = 0; r < 4; ++r) {
                size_t row = row0 + wr * 64 + m * 16 + rg + r;
                size_t col = col0 + wc * 64 + n * 16 + rl;
                G[row * N_TOT + col] = acc[m][n][r];
            }
}

// ---------------- 4: class-pair distance sums T[c1][c2] over full NxN ----------------
__global__ __launch_bounds__(256) void tsum_kernel(
        const float* __restrict__ G, const float* __restrict__ norms,
        const int* __restrict__ albl, const int* __restrict__ nlbl, float* __restrict__ T) {
    __shared__ float tl[NCLS * NCLS];
    int tid = threadIdx.x;
    for (int x = tid; x < NCLS * NCLS; x += 256) tl[x] = 0.f;
    __syncthreads();
    int r0 = blockIdx.x * 8;
    for (int r = r0; r < r0 + 8; ++r) {
        int lr = label_of(r, albl, nlbl);
        float nr = norms[r];
        const float* Grow = G + (size_t)r * N_TOT;
        for (int j = tid; j < N_TOT; j += 256) {
            float d2 = nr + norms[j] - 2.f * Grow[j];
            float dd = sqrtf(fmaxf(d2, 1e-8f));
            int lj = label_of(j, albl, nlbl);
            atomicAdd(&tl[lr * NCLS + lj], dd);
        }
    }
    __syncthreads();
    for (int x = tid; x < NCLS * NCLS; x += 256) {
        float v = tl[x];
        if (v != 0.f) atomicAdd(&T[x], v);
    }
}

// ---------------- 5: per-row hard mining + successor ("sort+searchsorted") term ----------------
__global__ __launch_bounds__(256) void row_kernel(
        const float* __restrict__ G, const float* __restrict__ norms,
        const int* __restrict__ albl, const int* __restrict__ nlbl, float* __restrict__ scal) {
    __shared__ float d[N_TOT];
    __shared__ unsigned char flg[N_TOT];   // 0 = negative, 1 = positive, 2 = self
    __shared__ int plist[512];
    __shared__ int pcount;
    __shared__ float sred[256];
    int i = blockIdx.x, tid = threadIdx.x;
    if (tid == 0) pcount = 0;
    __syncthreads();
    int la = albl[i];
    float ni = norms[i];
    const float* Grow = G + (size_t)i * N_TOT;
    float hp = -BIG_F, hn = BIG_F;
    for (int j = tid; j < N_TOT; j += 256) {
        float d2 = ni + norms[j] - 2.f * Grow[j];
        float dd = sqrtf(fmaxf(d2, 1e-8f));
        d[j] = dd;
        int lj = label_of(j, albl, nlbl);
        unsigned char f = (lj == la) ? ((j == i) ? (unsigned char)2 : (unsigned char)1) : (unsigned char)0;
        flg[j] = f;
        if (f == 1) {
            hp = fmaxf(hp, dd);
            int p = atomicAdd(&pcount, 1);
            if (p < 512) plist[p] = j;
        } else if (f == 0) {
            hn = fminf(hn, dd);
        }
    }
    float hpAll = block_reduce_max(hp, sred);
    float hnAll = block_reduce_min(hn, sred);
    int P = pcount;
    // successor query per positive: cand = min{ d[k] : k negative, d[k] > q }  (== searchsorted right)
    float sh_s = 0.f, sh_c = 0.f;
    for (int t = tid; t < P && t < 512; t += 256) {
        int jp = plist[t];
        float q = d[jp];
        float cand = BIG_F;
        for (int k = 0; k < N_TOT; ++k) {
            if (flg[k] == 0) {
                float v = d[k];
                if (v > q) cand = fminf(cand, v);
            }
        }
        if (cand < BIG_F && cand < q + MARGIN_F) { sh_s += q - cand + MARGIN_F; sh_c += 1.f; }
    }
    float shS = block_reduce_sum(sh_s, sred);
    float shC = block_reduce_sum(sh_c, sred);
    if (tid == 0) {
        bool hasP = (P > 0);
        bool hasN = (hnAll < BIG_F);
        if (hasP && hasN) {
            atomicAdd(&scal[1], fmaxf(hpAll - hnAll + MARGIN_F, 0.f));
            atomicAdd(&scal[2], 1.f);
        }
        if (shS != 0.f || shC != 0.f) {
            atomicAdd(&scal[3], shS);
            atomicAdd(&scal[4], shC);
        }
    }
}

// ---------------- 6: finalize: counts, intra/inter, combine ----------------
__global__ __launch_bounds__(256) void finalize_kernel(
        const float* __restrict__ T, const int* __restrict__ albl, const int* __restrict__ nlbl,
        const float* __restrict__ scal, float* __restrict__ out) {
    __shared__ int counts[NCLS];
    __shared__ int inA[NCLS];
    __shared__ float sred[256];
    int tid = threadIdx.x;
    if (tid < NCLS) { counts[tid] = 0; inA[tid] = 0; }
    __syncthreads();
    for (int i = tid; i < B_DIM; i += 256) {
        atomicAdd(&counts[albl[i]], 2);   // anchor + positive share the label
        inA[albl[i]] = 1;
        atomicAdd(&counts[nlbl[i]], 1);
    }
    __syncthreads();
    float intra = 0.f;
    if (tid < NCLS) {
        int c = tid;
        float cnt = (float)counts[c];
        if (inA[c] && counts[c] > 1)
            intra = T[c * NCLS + c] / fmaxf(cnt * (cnt - 1.f), 1.f);
    }
    float inter = 0.f;
    for (int x = tid; x < NCLS * NCLS; x += 256) {
        int c1 = x >> 6, c2 = x & 63;
        if (c1 < c2 && inA[c1] && inA[c2]) {
            float pn = (float)counts[c1] * (float)counts[c2];
            if (pn > 0.f) inter += fmaxf(MARGIN_F - T[x] / fmaxf(pn, 1.f), 0.f);
        }
    }
    float intraAll = block_reduce_sum(intra, sred);
    float interAll = block_reduce_sum(inter, sred);
    if (tid == 0) {
        float trip = scal[0] / (float)B_DIM;
        float hard = (scal[2] > 0.f) ? scal[1] / fmaxf(scal[2], 1.f) : 0.f;
        float sh   = (scal[4] > 0.f) ? scal[3] / fmaxf(scal[4], 1.f) : 0.f;
        out[0] = trip + hard + sh + 0.1f * intraAll + 0.1f * interAll;
    }
}

// ---------------- launch ----------------
extern "C" void kernel_launch(void* const* d_in, const int* in_sizes, int n_in,
                              void* d_out, int out_size, void* d_ws, size_t ws_size,
                              hipStream_t stream) {
    const float* A  = (const float*)d_in[0];
    const float* P  = (const float*)d_in[1];
    const float* Ng = (const float*)d_in[2];
    const int* albl = (const int*)d_in[3];
    const int* nlbl = (const int*)d_in[4];
    char* ws = (char*)d_ws;
    // workspace layout (bytes)
    __bf16* Eb   = (__bf16*)(ws);                     // 3072*2048*2 = 12,582,912
    float* G     = (float*)(ws + 12582912);           // 3072*3072*4 = 37,748,736
    float* norms = (float*)(ws + 50331648);           // 3072*4
    float* T     = (float*)(ws + 50343936);           // 64*64*4
    float* scal  = (float*)(ws + 50360320);           // 8 floats
    float* out   = (float*)d_out;

    hipLaunchKernelGGL(zero_kernel, dim3(16), dim3(256), 0, stream, T, scal);
    hipLaunchKernelGGL(convert_norms_kernel, dim3(N_TOT), dim3(256), 0, stream, A, P, Ng, Eb, norms);
    hipLaunchKernelGGL(triplet_kernel, dim3(B_DIM), dim3(256), 0, stream, A, P, Ng, scal);
    hipLaunchKernelGGL(gram_gemm, dim3((N_TOT / 128) * (N_TOT / 128)), dim3(256), 0, stream, Eb, G);
    hipLaunchKernelGGL(tsum_kernel, dim3(N_TOT / 8), dim3(256), 0, stream, G, norms, albl, nlbl, T);
    hipLaunchKernelGGL(row_kernel, dim3(B_DIM), dim3(256), 0, stream, G, norms, albl, nlbl, scal);
    hipLaunchKernelGGL(finalize_kernel, dim3(1), dim3(256), 0, stream, T, albl, nlbl, scal, out);
}

// Round 2
// 333.691 us; speedup vs baseline: 1.6495x; 1.6495x over previous
//
#include <hip/hip_runtime.h>
#include <hip/hip_bf16.h>
#include <stdint.h>

#define D_DIM 2048
#define B_DIM 1024
#define N_TOT 3072
#define NCLS 64
#define MARGIN_F 0.8f
#define BIG_F 1e30f
#define LDT 40   // LDS row stride (elements) for GEMM tiles: 80B rows -> <=2-way bank aliasing, 16B aligned

typedef float f32x4 __attribute__((ext_vector_type(4)));
typedef __bf16 bf16x8 __attribute__((ext_vector_type(8)));

// ---------------- block reduction helpers ----------------
__device__ inline float block_reduce_sum(float v, float* sred) {
    int tid = threadIdx.x;
    sred[tid] = v; __syncthreads();
    for (int s = 128; s > 0; s >>= 1) {
        if (tid < s) sred[tid] = sred[tid] + sred[tid + s];
        __syncthreads();
    }
    float r = sred[0]; __syncthreads();
    return r;
}
__device__ inline float block_reduce_max(float v, float* sred) {
    int tid = threadIdx.x;
    sred[tid] = v; __syncthreads();
    for (int s = 128; s > 0; s >>= 1) {
        if (tid < s) sred[tid] = fmaxf(sred[tid], sred[tid + s]);
        __syncthreads();
    }
    float r = sred[0]; __syncthreads();
    return r;
}
__device__ inline float block_reduce_min(float v, float* sred) {
    int tid = threadIdx.x;
    sred[tid] = v; __syncthreads();
    for (int s = 128; s > 0; s >>= 1) {
        if (tid < s) sred[tid] = fminf(sred[tid], sred[tid + s]);
        __syncthreads();
    }
    float r = sred[0]; __syncthreads();
    return r;
}

__device__ inline int label_of(int j, const int* __restrict__ albl, const int* __restrict__ nlbl) {
    return (j < 2 * B_DIM) ? albl[j & (B_DIM - 1)] : nlbl[j - 2 * B_DIM];
}

// ---------------- 0: zero accumulators ----------------
__global__ __launch_bounds__(256) void zero_kernel(float* __restrict__ T, float* __restrict__ scal) {
    int t = blockIdx.x * 256 + threadIdx.x;
    if (t < NCLS * NCLS) T[t] = 0.f;
    if (t < 8) scal[t] = 0.f;
}

// ---------------- 1: fp32 -> bf16 embed matrix + exact fp32 row norms ----------------
__global__ __launch_bounds__(256) void convert_norms_kernel(
        const float* __restrict__ A, const float* __restrict__ P, const float* __restrict__ Ng,
        __bf16* __restrict__ Eb, float* __restrict__ norms) {
    __shared__ float sred[256];
    int i = blockIdx.x;
    int tid = threadIdx.x;
    const float* src = (i < B_DIM) ? (A + (size_t)i * D_DIM)
                     : (i < 2 * B_DIM) ? (P + (size_t)(i - B_DIM) * D_DIM)
                     : (Ng + (size_t)(i - 2 * B_DIM) * D_DIM);
    const f32x4* s4 = (const f32x4*)src;
    f32x4 v0 = s4[tid * 2];
    f32x4 v1 = s4[tid * 2 + 1];
    float ss = v0[0]*v0[0] + v0[1]*v0[1] + v0[2]*v0[2] + v0[3]*v0[3]
             + v1[0]*v1[0] + v1[1]*v1[1] + v1[2]*v1[2] + v1[3]*v1[3];
    float vals[8] = {v0[0], v0[1], v0[2], v0[3], v1[0], v1[1], v1[2], v1[3]};
    bf16x8 o;
    #pragma unroll
    for (int e = 0; e < 8; ++e) o[e] = (__bf16)vals[e];
    *(bf16x8*)(Eb + (size_t)i * D_DIM + tid * 8) = o;
    float tot = block_reduce_sum(ss, sred);
    if (tid == 0) norms[i] = tot;
}

// ---------------- 2: exact fp32 triplet term ----------------
__global__ __launch_bounds__(256) void triplet_kernel(
        const float* __restrict__ A, const float* __restrict__ P, const float* __restrict__ Ng,
        float* __restrict__ scal) {
    __shared__ float sred[256];
    int i = blockIdx.x, tid = threadIdx.x;
    const f32x4* a4 = (const f32x4*)(A + (size_t)i * D_DIM);
    const f32x4* p4 = (const f32x4*)(P + (size_t)i * D_DIM);
    const f32x4* n4 = (const f32x4*)(Ng + (size_t)i * D_DIM);
    float pd = 0.f, nd = 0.f;
    for (int k = tid; k < D_DIM / 4; k += 256) {
        f32x4 av = a4[k], pv = p4[k], nv = n4[k];
        f32x4 dp = av - pv, dn = av - nv;
        pd += dp[0]*dp[0] + dp[1]*dp[1] + dp[2]*dp[2] + dp[3]*dp[3];
        nd += dn[0]*dn[0] + dn[1]*dn[1] + dn[2]*dn[2] + dn[3]*dn[3];
    }
    float pall = block_reduce_sum(pd, sred);
    float nall = block_reduce_sum(nd, sred);
    if (tid == 0) atomicAdd(&scal[0], fmaxf(pall - nall + MARGIN_F, 0.f));
}

// ---------------- 3: bf16 MFMA Gram: G = E * E^T  (128x128 tile, 4 waves, reg-staged LDS) ----------------
__global__ __launch_bounds__(256) void gram_gemm(const __bf16* __restrict__ Eb, float* __restrict__ G) {
    __shared__ __bf16 As[128 * LDT] __attribute__((aligned(16)));
    __shared__ __bf16 Bs[128 * LDT] __attribute__((aligned(16)));
    int tid = threadIdx.x;
    int lane = tid & 63, wave = tid >> 6;
    int bx = blockIdx.x % (N_TOT / 128);
    int by = blockIdx.x / (N_TOT / 128);
    size_t row0 = (size_t)by * 128, col0 = (size_t)bx * 128;
    int wr = wave >> 1, wc = wave & 1;          // wave -> 64x64 quadrant
    const f32x4 z4 = {0.f, 0.f, 0.f, 0.f};
    f32x4 acc[4][4];
    #pragma unroll
    for (int m = 0; m < 4; ++m)
        #pragma unroll
        for (int n = 0; n < 4; ++n) acc[m][n] = z4;

    int r_a = tid >> 2;          // staging row within [0,64)
    int c_a = (tid & 3) * 8;     // staging col 0/8/16/24
    const __bf16* arow = Eb + row0 * D_DIM;
    const __bf16* brow = Eb + col0 * D_DIM;
    int rl = lane & 15;
    int kg = (lane >> 4) * 8;    // k-offset of this lane's fragment

    for (int k0 = 0; k0 < D_DIM; k0 += 32) {
        bf16x8 a0 = *(const bf16x8*)(arow + (size_t)r_a * D_DIM + k0 + c_a);
        bf16x8 a1 = *(const bf16x8*)(arow + (size_t)(r_a + 64) * D_DIM + k0 + c_a);
        bf16x8 b0 = *(const bf16x8*)(brow + (size_t)r_a * D_DIM + k0 + c_a);
        bf16x8 b1 = *(const bf16x8*)(brow + (size_t)(r_a + 64) * D_DIM + k0 + c_a);
        __syncthreads();   // previous iteration's LDS reads done before overwrite
        *(bf16x8*)&As[r_a * LDT + c_a] = a0;
        *(bf16x8*)&As[(r_a + 64) * LDT + c_a] = a1;
        *(bf16x8*)&Bs[r_a * LDT + c_a] = b0;
        *(bf16x8*)&Bs[(r_a + 64) * LDT + c_a] = b1;
        __syncthreads();
        bf16x8 af[4], bf[4];
        #pragma unroll
        for (int m = 0; m < 4; ++m)
            af[m] = *(const bf16x8*)&As[(wr * 64 + m * 16 + rl) * LDT + kg];
        #pragma unroll
        for (int n = 0; n < 4; ++n)
            bf[n] = *(const bf16x8*)&Bs[(wc * 64 + n * 16 + rl) * LDT + kg];
        #pragma unroll
        for (int m = 0; m < 4; ++m)
            #pragma unroll
            for (int n = 0; n < 4; ++n)
                acc[m][n] = __builtin_amdgcn_mfma_f32_16x16x32_bf16(af[m], bf[n], acc[m][n], 0, 0, 0);
    }
    // C/D layout (HW-verified): col = lane&15, row = (lane>>4)*4 + reg
    int rg = (lane >> 4) * 4;
    #pragma unroll
    for (int m = 0; m < 4; ++m)
        #pragma unroll
        for (int n = 0; n < 4; ++n)
            #pragma unroll
            for (int r = 0; r < 4; ++r) {
                size_t row = row0 + wr * 64 + m * 16 + rg + r;
                size_t col = col0 + wc * 64 + n * 16 + rl;
                G[row * N_TOT + col] = acc[m][n][r];
            }
}

// ---------------- 4: class-pair distance sums T[c1][c2] over full NxN ----------------
__global__ __launch_bounds__(256) void tsum_kernel(
        const float* __restrict__ G, const float* __restrict__ norms,
        const int* __restrict__ albl, const int* __restrict__ nlbl, float* __restrict__ T) {
    __shared__ float tl[NCLS * NCLS];
    int tid = threadIdx.x;
    for (int x = tid; x < NCLS * NCLS; x += 256) tl[x] = 0.f;
    __syncthreads();
    int r0 = blockIdx.x * 8;
    for (int r = r0; r < r0 + 8; ++r) {
        int lr = label_of(r, albl, nlbl);
        float nr = norms[r];
        const float* Grow = G + (size_t)r * N_TOT;
        for (int j = tid; j < N_TOT; j += 256) {
            float d2 = nr + norms[j] - 2.f * Grow[j];
            float dd = sqrtf(fmaxf(d2, 1e-8f));
            int lj = label_of(j, albl, nlbl);
            atomicAdd(&tl[lr * NCLS + lj], dd);
        }
    }
    __syncthreads();
    for (int x = tid; x < NCLS * NCLS; x += 256) {
        float v = tl[x];
        if (v != 0.f) atomicAdd(&T[x], v);
    }
}

// ---------------- 5: per-row hard mining + successor term (wave-parallel scan) ----------------
// Previous version: one thread per positive scanned all 3072 LDS entries serially
// (48/64 lanes idle, latency-bound, 322 us). Now: each wave owns positives
// p = wave, wave+4, ...; all 64 lanes scan a lane-strided slice of dneg[] and
// shuffle-reduce the successor min. dneg[] merges distance+mask (non-negatives = BIG),
// removing the flag read and branch from the inner loop.
__global__ __launch_bounds__(256) void row_kernel(
        const float* __restrict__ G, const float* __restrict__ norms,
        const int* __restrict__ albl, const int* __restrict__ nlbl, float* __restrict__ scal) {
    __shared__ float dneg[N_TOT];     // negatives: distance; positives/self: BIG
    __shared__ float qlist[256];      // query distances of this row's positives
    __shared__ float sred[256];
    __shared__ float wpart[8];
    __shared__ int pcount;
    int i = blockIdx.x, tid = threadIdx.x;
    int lane = tid & 63, wave = tid >> 6;
    if (tid == 0) pcount = 0;
    __syncthreads();
    int la = albl[i];
    float ni = norms[i];
    const float* Grow = G + (size_t)i * N_TOT;
    float hp = -BIG_F, hn = BIG_F;
    for (int j = tid; j < N_TOT; j += 256) {
        float d2 = ni + norms[j] - 2.f * Grow[j];
        float dd = sqrtf(fmaxf(d2, 1e-8f));
        int lj = label_of(j, albl, nlbl);
        bool isN = (lj != la);
        bool isP = (lj == la) && (j != i);
        dneg[j] = isN ? dd : BIG_F;
        if (isN) hn = fminf(hn, dd);
        if (isP) {
            hp = fmaxf(hp, dd);
            int p = atomicAdd(&pcount, 1);
            if (p < 256) qlist[p] = dd;
        }
    }
    float hpAll = block_reduce_max(hp, sred);
    float hnAll = block_reduce_min(hn, sred);   // barriers inside also publish dneg/qlist
    int P = min(pcount, 256);
    float sh_s = 0.f, sh_c = 0.f;
    for (int p = wave; p < P; p += 4) {
        float q = qlist[p];
        float c = BIG_F;
        #pragma unroll 8
        for (int kk = 0; kk < N_TOT / 64; ++kk) {
            float v = dneg[kk * 64 + lane];       // stride-1 across lanes: conflict-free
            c = fminf(c, (v > q) ? v : BIG_F);
        }
        #pragma unroll
        for (int off = 32; off > 0; off >>= 1)
            c = fminf(c, __shfl_down(c, off));
        if (lane == 0 && c < BIG_F && c < q + MARGIN_F) {
            sh_s += q - c + MARGIN_F; sh_c += 1.f;
        }
    }
    if (lane == 0) { wpart[wave] = sh_s; wpart[4 + wave] = sh_c; }
    __syncthreads();
    if (tid == 0) {
        float shS = wpart[0] + wpart[1] + wpart[2] + wpart[3];
        float shC = wpart[4] + wpart[5] + wpart[6] + wpart[7];
        bool hasP = (P > 0), hasN = (hnAll < BIG_F);
        if (hasP && hasN) {
            atomicAdd(&scal[1], fmaxf(hpAll - hnAll + MARGIN_F, 0.f));
            atomicAdd(&scal[2], 1.f);
        }
        if (shS != 0.f || shC != 0.f) {
            atomicAdd(&scal[3], shS);
            atomicAdd(&scal[4], shC);
        }
    }
}

// ---------------- 6: finalize: counts, intra/inter, combine ----------------
__global__ __launch_bounds__(256) void finalize_kernel(
        const float* __restrict__ T, const int* __restrict__ albl, const int* __restrict__ nlbl,
        const float* __restrict__ scal, float* __restrict__ out) {
    __shared__ int counts[NCLS];
    __shared__ int inA[NCLS];
    __shared__ float sred[256];
    int tid = threadIdx.x;
    if (tid < NCLS) { counts[tid] = 0; inA[tid] = 0; }
    __syncthreads();
    for (int i = tid; i < B_DIM; i += 256) {
        atomicAdd(&counts[albl[i]], 2);   // anchor + positive share the label
        inA[albl[i]] = 1;
        atomicAdd(&counts[nlbl[i]], 1);
    }
    __syncthreads();
    float intra = 0.f;
    if (tid < NCLS) {
        int c = tid;
        float cnt = (float)counts[c];
        if (inA[c] && counts[c] > 1)
            intra = T[c * NCLS + c] / fmaxf(cnt * (cnt - 1.f), 1.f);
    }
    float inter = 0.f;
    for (int x = tid; x < NCLS * NCLS; x += 256) {
        int c1 = x >> 6, c2 = x & 63;
        if (c1 < c2 && inA[c1] && inA[c2]) {
            float pn = (float)counts[c1] * (float)counts[c2];
            if (pn > 0.f) inter += fmaxf(MARGIN_F - T[x] / fmaxf(pn, 1.f), 0.f);
        }
    }
    float intraAll = block_reduce_sum(intra, sred);
    float interAll = block_reduce_sum(inter, sred);
    if (tid == 0) {
        float trip = scal[0] / (float)B_DIM;
        float hard = (scal[2] > 0.f) ? scal[1] / fmaxf(scal[2], 1.f) : 0.f;
        float sh   = (scal[4] > 0.f) ? scal[3] / fmaxf(scal[4], 1.f) : 0.f;
        out[0] = trip + hard + sh + 0.1f * intraAll + 0.1f * interAll;
    }
}

// ---------------- launch ----------------
extern "C" void kernel_launch(void* const* d_in, const int* in_sizes, int n_in,
                              void* d_out, int out_size, void* d_ws, size_t ws_size,
                              hipStream_t stream) {
    const float* A  = (const float*)d_in[0];
    const float* P  = (const float*)d_in[1];
    const float* Ng = (const float*)d_in[2];
    const int* albl = (const int*)d_in[3];
    const int* nlbl = (const int*)d_in[4];
    char* ws = (char*)d_ws;
    // workspace layout (bytes)
    __bf16* Eb   = (__bf16*)(ws);                     // 3072*2048*2 = 12,582,912
    float* G     = (float*)(ws + 12582912);           // 3072*3072*4 = 37,748,736
    float* norms = (float*)(ws + 50331648);           // 3072*4
    float* T     = (float*)(ws + 50343936);           // 64*64*4
    float* scal  = (float*)(ws + 50360320);           // 8 floats
    float* out   = (float*)d_out;

    hipLaunchKernelGGL(zero_kernel, dim3(16), dim3(256), 0, stream, T, scal);
    hipLaunchKernelGGL(convert_norms_kernel, dim3(N_TOT), dim3(256), 0, stream, A, P, Ng, Eb, norms);
    hipLaunchKernelGGL(triplet_kernel, dim3(B_DIM), dim3(256), 0, stream, A, P, Ng, scal);
    hipLaunchKernelGGL(gram_gemm, dim3((N_TOT / 128) * (N_TOT / 128)), dim3(256), 0, stream, Eb, G);
    hipLaunchKernelGGL(tsum_kernel, dim3(N_TOT / 8), dim3(256), 0, stream, G, norms, albl, nlbl, T);
    hipLaunchKernelGGL(row_kernel, dim3(B_DIM), dim3(256), 0, stream, G, norms, albl, nlbl, scal);
    hipLaunchKernelGGL(finalize_kernel, dim3(1), dim3(256), 0, stream, T, albl, nlbl, scal, out);
}

// Round 4
// 288.006 us; speedup vs baseline: 1.9112x; 1.1586x over previous
//
#include <hip/hip_runtime.h>
#include <hip/hip_bf16.h>
#include <stdint.h>

#define D_DIM 2048
#define B_DIM 1024
#define N_TOT 3072
#define NCLS 64
#define NB128 (N_TOT / 128)   // 24 tiles per side
#define MARGIN_F 0.8f
#define BIG_F 1e30f
#define LDT 40   // LDS row stride (elements) for GEMM tiles: 80B rows, 16B aligned

typedef float f32x4 __attribute__((ext_vector_type(4)));
typedef __bf16 bf16x8 __attribute__((ext_vector_type(8)));

// ---------------- reduction helpers ----------------
__device__ inline float block_reduce_sum(float v, float* sred) {
    int tid = threadIdx.x;
    sred[tid] = v; __syncthreads();
    for (int s = 128; s > 0; s >>= 1) {
        if (tid < s) sred[tid] = sred[tid] + sred[tid + s];
        __syncthreads();
    }
    float r = sred[0]; __syncthreads();
    return r;
}
__device__ inline float block_reduce_max(float v, float* sred) {
    int tid = threadIdx.x;
    sred[tid] = v; __syncthreads();
    for (int s = 128; s > 0; s >>= 1) {
        if (tid < s) sred[tid] = fmaxf(sred[tid], sred[tid + s]);
        __syncthreads();
    }
    float r = sred[0]; __syncthreads();
    return r;
}
__device__ inline float block_reduce_min(float v, float* sred) {
    int tid = threadIdx.x;
    sred[tid] = v; __syncthreads();
    for (int s = 128; s > 0; s >>= 1) {
        if (tid < s) sred[tid] = fminf(sred[tid], sred[tid + s]);
        __syncthreads();
    }
    float r = sred[0]; __syncthreads();
    return r;
}
// cheap 2-barrier block sum (wave shuffle + cross-wave LDS)
__device__ inline float block_sum4(float v, float* tmp4, int lane, int wave) {
    #pragma unroll
    for (int off = 32; off > 0; off >>= 1) v += __shfl_down(v, off);
    __syncthreads();                 // protect tmp4 reuse across calls
    if (lane == 0) tmp4[wave] = v;
    __syncthreads();
    return tmp4[0] + tmp4[1] + tmp4[2] + tmp4[3];
}

__device__ inline int label_of(int j, const int* __restrict__ albl, const int* __restrict__ nlbl) {
    return (j < 2 * B_DIM) ? albl[j & (B_DIM - 1)] : nlbl[j - 2 * B_DIM];
}

__device__ inline float sq8(f32x4 a, f32x4 b) {
    return a[0]*a[0] + a[1]*a[1] + a[2]*a[2] + a[3]*a[3]
         + b[0]*b[0] + b[1]*b[1] + b[2]*b[2] + b[3]*b[3];
}
__device__ inline void st_bf8(__bf16* dst, f32x4 v0, f32x4 v1) {
    bf16x8 o;
    o[0] = (__bf16)v0[0]; o[1] = (__bf16)v0[1]; o[2] = (__bf16)v0[2]; o[3] = (__bf16)v0[3];
    o[4] = (__bf16)v1[0]; o[5] = (__bf16)v1[1]; o[6] = (__bf16)v1[2]; o[7] = (__bf16)v1[3];
    *(bf16x8*)dst = o;
}

// ---------------- 0: zero accumulators ----------------
__global__ __launch_bounds__(256) void zero_kernel(float* __restrict__ T, float* __restrict__ scal) {
    int t = blockIdx.x * 256 + threadIdx.x;
    if (t < NCLS * NCLS) T[t] = 0.f;
    if (t < 8) scal[t] = 0.f;
}

// ---------------- 1: fused prep: bf16 convert + norms + exact triplet term ----------------
// One block per row index i: handles rows i (A), B+i (P), 2B+i (N). Reads A/P/N once.
__global__ __launch_bounds__(256) void prep_kernel(
        const float* __restrict__ A, const float* __restrict__ P, const float* __restrict__ Ng,
        __bf16* __restrict__ Eb, float* __restrict__ norms, float* __restrict__ scal) {
    __shared__ float tmp4[4];
    int i = blockIdx.x, tid = threadIdx.x;
    int lane = tid & 63, wave = tid >> 6;
    const f32x4* a4 = (const f32x4*)(A + (size_t)i * D_DIM);
    const f32x4* p4 = (const f32x4*)(P + (size_t)i * D_DIM);
    const f32x4* n4 = (const f32x4*)(Ng + (size_t)i * D_DIM);
    f32x4 av0 = a4[tid * 2], av1 = a4[tid * 2 + 1];
    f32x4 pv0 = p4[tid * 2], pv1 = p4[tid * 2 + 1];
    f32x4 nv0 = n4[tid * 2], nv1 = n4[tid * 2 + 1];
    float sa = sq8(av0, av1), sp = sq8(pv0, pv1), sn = sq8(nv0, nv1);
    f32x4 dp0 = av0 - pv0, dp1 = av1 - pv1;
    f32x4 dn0 = av0 - nv0, dn1 = av1 - nv1;
    float pd = sq8(dp0, dp1), nd = sq8(dn0, dn1);
    st_bf8(Eb + (size_t)i * D_DIM + tid * 8, av0, av1);
    st_bf8(Eb + (size_t)(B_DIM + i) * D_DIM + tid * 8, pv0, pv1);
    st_bf8(Eb + (size_t)(2 * B_DIM + i) * D_DIM + tid * 8, nv0, nv1);
    float saT = block_sum4(sa, tmp4, lane, wave);
    float spT = block_sum4(sp, tmp4, lane, wave);
    float snT = block_sum4(sn, tmp4, lane, wave);
    float pdT = block_sum4(pd, tmp4, lane, wave);
    float ndT = block_sum4(nd, tmp4, lane, wave);
    if (tid == 0) {
        norms[i] = saT;
        norms[B_DIM + i] = spT;
        norms[2 * B_DIM + i] = snT;
        atomicAdd(&scal[0], fmaxf(pdT - ndT + MARGIN_F, 0.f));
    }
}

// ---------------- 2: bf16 MFMA Gram, upper 128-block triangle only ----------------
__global__ __launch_bounds__(256) void gram_gemm(const __bf16* __restrict__ Eb, float* __restrict__ G) {
    __shared__ __bf16 As[128 * LDT] __attribute__((aligned(16)));
    __shared__ __bf16 Bs[128 * LDT] __attribute__((aligned(16)));
    int tid = threadIdx.x;
    int lane = tid & 63, wave = tid >> 6;
    // decode upper-triangle pair (by <= bx) from linear blockIdx over 300 blocks
    int by = 0, rem = blockIdx.x;
    while (rem >= NB128 - by) { rem -= (NB128 - by); ++by; }
    int bx = by + rem;
    size_t row0 = (size_t)by * 128, col0 = (size_t)bx * 128;
    int wr = wave >> 1, wc = wave & 1;          // wave -> 64x64 quadrant
    const f32x4 z4 = {0.f, 0.f, 0.f, 0.f};
    f32x4 acc[4][4];
    #pragma unroll
    for (int m = 0; m < 4; ++m)
        #pragma unroll
        for (int n = 0; n < 4; ++n) acc[m][n] = z4;

    int r_a = tid >> 2;          // staging row within [0,64)
    int c_a = (tid & 3) * 8;     // staging col 0/8/16/24
    const __bf16* arow = Eb + row0 * D_DIM;
    const __bf16* brow = Eb + col0 * D_DIM;
    int rl = lane & 15;
    int kg = (lane >> 4) * 8;    // k-offset of this lane's fragment

    for (int k0 = 0; k0 < D_DIM; k0 += 32) {
        bf16x8 a0 = *(const bf16x8*)(arow + (size_t)r_a * D_DIM + k0 + c_a);
        bf16x8 a1 = *(const bf16x8*)(arow + (size_t)(r_a + 64) * D_DIM + k0 + c_a);
        bf16x8 b0 = *(const bf16x8*)(brow + (size_t)r_a * D_DIM + k0 + c_a);
        bf16x8 b1 = *(const bf16x8*)(brow + (size_t)(r_a + 64) * D_DIM + k0 + c_a);
        __syncthreads();   // previous iteration's LDS reads done before overwrite
        *(bf16x8*)&As[r_a * LDT + c_a] = a0;
        *(bf16x8*)&As[(r_a + 64) * LDT + c_a] = a1;
        *(bf16x8*)&Bs[r_a * LDT + c_a] = b0;
        *(bf16x8*)&Bs[(r_a + 64) * LDT + c_a] = b1;
        __syncthreads();
        bf16x8 af[4], bf[4];
        #pragma unroll
        for (int m = 0; m < 4; ++m)
            af[m] = *(const bf16x8*)&As[(wr * 64 + m * 16 + rl) * LDT + kg];
        #pragma unroll
        for (int n = 0; n < 4; ++n)
            bf[n] = *(const bf16x8*)&Bs[(wc * 64 + n * 16 + rl) * LDT + kg];
        #pragma unroll
        for (int m = 0; m < 4; ++m)
            #pragma unroll
            for (int n = 0; n < 4; ++n)
                acc[m][n] = __builtin_amdgcn_mfma_f32_16x16x32_bf16(af[m], bf[n], acc[m][n], 0, 0, 0);
    }
    // C/D layout (HW-verified): col = lane&15, row = (lane>>4)*4 + reg
    int rg = (lane >> 4) * 4;
    #pragma unroll
    for (int m = 0; m < 4; ++m)
        #pragma unroll
        for (int n = 0; n < 4; ++n)
            #pragma unroll
            for (int r = 0; r < 4; ++r) {
                size_t row = row0 + wr * 64 + m * 16 + rg + r;
                size_t col = col0 + wc * 64 + n * 16 + rl;
                G[row * N_TOT + col] = acc[m][n][r];
            }
}

// ---------------- 3: mirror upper triangle into lower (64x64 LDS transpose tiles) ----------------
// Covers all 64-tiles strictly below the 128-block diagonal (diag 128-blocks are fully
// written by gram_gemm). Grid = 276 pairs * 4 quadrants = 1104 blocks.
__global__ __launch_bounds__(256) void mirror_kernel(float* __restrict__ G) {
    __shared__ float s[64 * 65];
    int b = blockIdx.x;
    int p = b >> 2, q = b & 3;
    int bj = 0, rem = p;                       // 128-block pair, bi > bj
    while (rem >= NB128 - 1 - bj) { rem -= (NB128 - 1 - bj); ++bj; }
    int bi = bj + 1 + rem;
    int ti = bi * 2 + (q >> 1), tj = bj * 2 + (q & 1);   // 64-tile coords (ti strictly below tj's block)
    int tid = threadIdx.x;
    int c = tid & 63, r4 = tid >> 6;
    const float* src = G + ((size_t)tj * 64) * N_TOT + (size_t)ti * 64;  // upper tile (tj,ti)
    float* dst = G + ((size_t)ti * 64) * N_TOT + (size_t)tj * 64;        // lower tile (ti,tj)
    #pragma unroll
    for (int rr = 0; rr < 16; ++rr) {
        int row = rr * 4 + r4;
        s[row * 65 + c] = src[(size_t)row * N_TOT + c];
    }
    __syncthreads();
    #pragma unroll
    for (int rr = 0; rr < 16; ++rr) {
        int row = rr * 4 + r4;
        dst[(size_t)row * N_TOT + c] = s[c * 65 + row];   // stride-65 read: conflict-free
    }
}

// ---------------- 4: class-pair distance sums T[c1][c2] over full NxN ----------------
__global__ __launch_bounds__(256) void tsum_kernel(
        const float* __restrict__ G, const float* __restrict__ norms,
        const int* __restrict__ albl, const int* __restrict__ nlbl, float* __restrict__ T) {
    __shared__ float tl[NCLS * NCLS];
    int tid = threadIdx.x;
    for (int x = tid; x < NCLS * NCLS; x += 256) tl[x] = 0.f;
    __syncthreads();
    int r0 = blockIdx.x * 8;
    for (int r = r0; r < r0 + 8; ++r) {
        int lr = label_of(r, albl, nlbl);
        float nr = norms[r];
        const float* Grow = G + (size_t)r * N_TOT;
        for (int j = tid; j < N_TOT; j += 256) {
            float d2 = nr + norms[j] - 2.f * Grow[j];
            float dd = sqrtf(fmaxf(d2, 1e-8f));
            int lj = label_of(j, albl, nlbl);
            atomicAdd(&tl[lr * NCLS + lj], dd);
        }
    }
    __syncthreads();
    for (int x = tid; x < NCLS * NCLS; x += 256) {
        float v = tl[x];
        if (v != 0.f) atomicAdd(&T[x], v);
    }
}

// ---------------- 5: per-row hard mining + successor term (query-per-lane broadcast scan) ----------------
// R2 was latency-bound: per-query lane-strided scans (48 queries x 48 iters per wave, serial
// min chains). Now one query per LANE: each wave streams a 768-element quarter of dneg[] with
// broadcast LDS reads (conflict-free), updating all <=64 queries simultaneously; 4 wave-partials
// combine via LDS. Per block: 3072 broadcast reads total instead of 48x3072 lane-visits.
__global__ __launch_bounds__(256) void row_kernel(
        const float* __restrict__ G, const float* __restrict__ norms,
        const int* __restrict__ albl, const int* __restrict__ nlbl, float* __restrict__ scal) {
    __shared__ float dneg[N_TOT];     // negatives: distance; positives/self: BIG
    __shared__ float qlist[128];      // query distances of this row's positives (P~48, cap 128)
    __shared__ float cpart[4 * 64];
    __shared__ float sred[256];
    __shared__ float acc2[2];
    __shared__ int pcount;
    int i = blockIdx.x, tid = threadIdx.x;
    int lane = tid & 63, wave = tid >> 6;
    if (tid == 0) { pcount = 0; acc2[0] = 0.f; acc2[1] = 0.f; }
    __syncthreads();
    int la = albl[i];
    float ni = norms[i];
    const float* Grow = G + (size_t)i * N_TOT;
    float hp = -BIG_F, hn = BIG_F;
    for (int j = tid; j < N_TOT; j += 256) {
        float d2 = ni + norms[j] - 2.f * Grow[j];
        float dd = sqrtf(fmaxf(d2, 1e-8f));
        int lj = label_of(j, albl, nlbl);
        bool isN = (lj != la);
        dneg[j] = isN ? dd : BIG_F;
        if (isN) {
            hn = fminf(hn, dd);
        } else if (j != i) {
            hp = fmaxf(hp, dd);
            int p = atomicAdd(&pcount, 1);
            if (p < 128) qlist[p] = dd;
        }
    }
    float hpAll = block_reduce_max(hp, sred);
    float hnAll = block_reduce_min(hn, sred);   // barriers also publish dneg/qlist/pcount
    int P = min(pcount, 128);
    const int CH = N_TOT / 4;                   // 768 elements per wave
    for (int q0 = 0; q0 < P; q0 += 64) {
        int nq = min(64, P - q0);
        float q = (lane < nq) ? qlist[q0 + lane] : BIG_F;   // BIG sentinel: never matched
        float c0 = BIG_F, c1 = BIG_F, c2 = BIG_F, c3 = BIG_F;
        int base = wave * CH;
        #pragma unroll 4
        for (int k = 0; k < CH; k += 4) {
            float v0 = dneg[base + k + 0];      // same addr across lanes: broadcast, no conflict
            float v1 = dneg[base + k + 1];
            float v2 = dneg[base + k + 2];
            float v3 = dneg[base + k + 3];
            c0 = fminf(c0, (v0 > q) ? v0 : BIG_F);
            c1 = fminf(c1, (v1 > q) ? v1 : BIG_F);
            c2 = fminf(c2, (v2 > q) ? v2 : BIG_F);
            c3 = fminf(c3, (v3 > q) ? v3 : BIG_F);
        }
        float c = fminf(fminf(c0, c1), fminf(c2, c3));
        cpart[wave * 64 + lane] = c;
        __syncthreads();
        if (wave == 0) {
            float cc = fminf(fminf(cpart[lane], cpart[64 + lane]),
                             fminf(cpart[128 + lane], cpart[192 + lane]));
            float s = 0.f, n = 0.f;
            if (lane < nq && cc < 1e29f) {
                float qq = qlist[q0 + lane];
                if (cc < qq + MARGIN_F) { s = qq - cc + MARGIN_F; n = 1.f; }
            }
            #pragma unroll
            for (int off = 32; off > 0; off >>= 1) {
                s += __shfl_down(s, off);
                n += __shfl_down(n, off);
            }
            if (lane == 0) { acc2[0] += s; acc2[1] += n; }
        }
        __syncthreads();
    }
    if (tid == 0) {
        if (P > 0 && hnAll < 1e29f) {
            atomicAdd(&scal[1], fmaxf(hpAll - hnAll + MARGIN_F, 0.f));
            atomicAdd(&scal[2], 1.f);
        }
        if (acc2[0] != 0.f || acc2[1] != 0.f) {
            atomicAdd(&scal[3], acc2[0]);
            atomicAdd(&scal[4], acc2[1]);
        }
    }
}

// ---------------- 6: finalize: counts, intra/inter, combine ----------------
__global__ __launch_bounds__(256) void finalize_kernel(
        const float* __restrict__ T, const int* __restrict__ albl, const int* __restrict__ nlbl,
        const float* __restrict__ scal, float* __restrict__ out) {
    __shared__ int counts[NCLS];
    __shared__ int inA[NCLS];
    __shared__ float sred[256];
    int tid = threadIdx.x;
    if (tid < NCLS) { counts[tid] = 0; inA[tid] = 0; }
    __syncthreads();
    for (int i = tid; i < B_DIM; i += 256) {
        atomicAdd(&counts[albl[i]], 2);   // anchor + positive share the label
        inA[albl[i]] = 1;
        atomicAdd(&counts[nlbl[i]], 1);
    }
    __syncthreads();
    float intra = 0.f;
    if (tid < NCLS) {
        int c = tid;
        float cnt = (float)counts[c];
        if (inA[c] && counts[c] > 1)
            intra = T[c * NCLS + c] / fmaxf(cnt * (cnt - 1.f), 1.f);
    }
    float inter = 0.f;
    for (int x = tid; x < NCLS * NCLS; x += 256) {
        int c1 = x >> 6, c2 = x & 63;
        if (c1 < c2 && inA[c1] && inA[c2]) {
            float pn = (float)counts[c1] * (float)counts[c2];
            if (pn > 0.f) inter += fmaxf(MARGIN_F - T[x] / fmaxf(pn, 1.f), 0.f);
        }
    }
    float intraAll = block_reduce_sum(intra, sred);
    float interAll = block_reduce_sum(inter, sred);
    if (tid == 0) {
        float trip = scal[0] / (float)B_DIM;
        float hard = (scal[2] > 0.f) ? scal[1] / fmaxf(scal[2], 1.f) : 0.f;
        float sh   = (scal[4] > 0.f) ? scal[3] / fmaxf(scal[4], 1.f) : 0.f;
        out[0] = trip + hard + sh + 0.1f * intraAll + 0.1f * interAll;
    }
}

// ---------------- launch ----------------
extern "C" void kernel_launch(void* const* d_in, const int* in_sizes, int n_in,
                              void* d_out, int out_size, void* d_ws, size_t ws_size,
                              hipStream_t stream) {
    const float* A  = (const float*)d_in[0];
    const float* P  = (const float*)d_in[1];
    const float* Ng = (const float*)d_in[2];
    const int* albl = (const int*)d_in[3];
    const int* nlbl = (const int*)d_in[4];
    char* ws = (char*)d_ws;
    // workspace layout (bytes)
    __bf16* Eb   = (__bf16*)(ws);                     // 3072*2048*2 = 12,582,912
    float* G     = (float*)(ws + 12582912);           // 3072*3072*4 = 37,748,736
    float* norms = (float*)(ws + 50331648);           // 3072*4
    float* T     = (float*)(ws + 50343936);           // 64*64*4
    float* scal  = (float*)(ws + 50360320);           // 8 floats
    float* out   = (float*)d_out;

    hipLaunchKernelGGL(zero_kernel, dim3(16), dim3(256), 0, stream, T, scal);
    hipLaunchKernelGGL(prep_kernel, dim3(B_DIM), dim3(256), 0, stream, A, P, Ng, Eb, norms, scal);
    hipLaunchKernelGGL(gram_gemm, dim3(NB128 * (NB128 + 1) / 2), dim3(256), 0, stream, Eb, G);
    hipLaunchKernelGGL(mirror_kernel, dim3((NB128 * (NB128 - 1) / 2) * 4), dim3(256), 0, stream, G);
    hipLaunchKernelGGL(tsum_kernel, dim3(N_TOT / 8), dim3(256), 0, stream, G, norms, albl, nlbl, T);
    hipLaunchKernelGGL(row_kernel, dim3(B_DIM), dim3(256), 0, stream, G, norms, albl, nlbl, scal);
    hipLaunchKernelGGL(finalize_kernel, dim3(1), dim3(256), 0, stream, T, albl, nlbl, scal, out);
}

// Round 5
// 259.642 us; speedup vs baseline: 2.1200x; 1.1092x over previous
//
#include <hip/hip_runtime.h>
#include <hip/hip_bf16.h>
#include <stdint.h>

#define D_DIM 2048
#define B_DIM 1024
#define N_TOT 3072
#define NCLS 64
#define NB128 (N_TOT / 128)   // 24 tiles per side
#define MARGIN_F 0.8f
#define BIG_F 1e30f
#define LDT 40   // LDS row stride (elements) for GEMM tiles: 80B rows, 16B aligned

typedef float f32x4 __attribute__((ext_vector_type(4)));
typedef __bf16 bf16x8 __attribute__((ext_vector_type(8)));

// ---------------- reduction helpers ----------------
__device__ inline float block_reduce_sum(float v, float* sred) {
    int tid = threadIdx.x;
    sred[tid] = v; __syncthreads();
    for (int s = 128; s > 0; s >>= 1) {
        if (tid < s) sred[tid] = sred[tid] + sred[tid + s];
        __syncthreads();
    }
    float r = sred[0]; __syncthreads();
    return r;
}
__device__ inline float block_reduce_max(float v, float* sred) {
    int tid = threadIdx.x;
    sred[tid] = v; __syncthreads();
    for (int s = 128; s > 0; s >>= 1) {
        if (tid < s) sred[tid] = fmaxf(sred[tid], sred[tid + s]);
        __syncthreads();
    }
    float r = sred[0]; __syncthreads();
    return r;
}
__device__ inline float block_reduce_min(float v, float* sred) {
    int tid = threadIdx.x;
    sred[tid] = v; __syncthreads();
    for (int s = 128; s > 0; s >>= 1) {
        if (tid < s) sred[tid] = fminf(sred[tid], sred[tid + s]);
        __syncthreads();
    }
    float r = sred[0]; __syncthreads();
    return r;
}
// cheap 2-barrier block sum (wave shuffle + cross-wave LDS)
__device__ inline float block_sum4(float v, float* tmp4, int lane, int wave) {
    #pragma unroll
    for (int off = 32; off > 0; off >>= 1) v += __shfl_down(v, off);
    __syncthreads();                 // protect tmp4 reuse across calls
    if (lane == 0) tmp4[wave] = v;
    __syncthreads();
    return tmp4[0] + tmp4[1] + tmp4[2] + tmp4[3];
}

__device__ inline int label_of(int j, const int* __restrict__ albl, const int* __restrict__ nlbl) {
    return (j < 2 * B_DIM) ? albl[j & (B_DIM - 1)] : nlbl[j - 2 * B_DIM];
}

__device__ inline float sq8(f32x4 a, f32x4 b) {
    return a[0]*a[0] + a[1]*a[1] + a[2]*a[2] + a[3]*a[3]
         + b[0]*b[0] + b[1]*b[1] + b[2]*b[2] + b[3]*b[3];
}
__device__ inline void st_bf8(__bf16* dst, f32x4 v0, f32x4 v1) {
    bf16x8 o;
    o[0] = (__bf16)v0[0]; o[1] = (__bf16)v0[1]; o[2] = (__bf16)v0[2]; o[3] = (__bf16)v0[3];
    o[4] = (__bf16)v1[0]; o[5] = (__bf16)v1[1]; o[6] = (__bf16)v1[2]; o[7] = (__bf16)v1[3];
    *(bf16x8*)dst = o;
}

// ---------------- 0: zero accumulators ----------------
__global__ __launch_bounds__(256) void zero_kernel(float* __restrict__ T, float* __restrict__ scal) {
    int t = blockIdx.x * 256 + threadIdx.x;
    if (t < NCLS * NCLS) T[t] = 0.f;
    if (t < 8) scal[t] = 0.f;
}

// ---------------- 1: fused prep: bf16 convert + norms + exact triplet term ----------------
__global__ __launch_bounds__(256) void prep_kernel(
        const float* __restrict__ A, const float* __restrict__ P, const float* __restrict__ Ng,
        __bf16* __restrict__ Eb, float* __restrict__ norms, float* __restrict__ scal) {
    __shared__ float tmp4[4];
    int i = blockIdx.x, tid = threadIdx.x;
    int lane = tid & 63, wave = tid >> 6;
    const f32x4* a4 = (const f32x4*)(A + (size_t)i * D_DIM);
    const f32x4* p4 = (const f32x4*)(P + (size_t)i * D_DIM);
    const f32x4* n4 = (const f32x4*)(Ng + (size_t)i * D_DIM);
    f32x4 av0 = a4[tid * 2], av1 = a4[tid * 2 + 1];
    f32x4 pv0 = p4[tid * 2], pv1 = p4[tid * 2 + 1];
    f32x4 nv0 = n4[tid * 2], nv1 = n4[tid * 2 + 1];
    float sa = sq8(av0, av1), sp = sq8(pv0, pv1), sn = sq8(nv0, nv1);
    f32x4 dp0 = av0 - pv0, dp1 = av1 - pv1;
    f32x4 dn0 = av0 - nv0, dn1 = av1 - nv1;
    float pd = sq8(dp0, dp1), nd = sq8(dn0, dn1);
    st_bf8(Eb + (size_t)i * D_DIM + tid * 8, av0, av1);
    st_bf8(Eb + (size_t)(B_DIM + i) * D_DIM + tid * 8, pv0, pv1);
    st_bf8(Eb + (size_t)(2 * B_DIM + i) * D_DIM + tid * 8, nv0, nv1);
    float saT = block_sum4(sa, tmp4, lane, wave);
    float spT = block_sum4(sp, tmp4, lane, wave);
    float snT = block_sum4(sn, tmp4, lane, wave);
    float pdT = block_sum4(pd, tmp4, lane, wave);
    float ndT = block_sum4(nd, tmp4, lane, wave);
    if (tid == 0) {
        norms[i] = saT;
        norms[B_DIM + i] = spT;
        norms[2 * B_DIM + i] = snT;
        atomicAdd(&scal[0], fmaxf(pdT - ndT + MARGIN_F, 0.f));
    }
}

// ---------------- 2: bf16 MFMA Gram, upper 128-block triangle only ----------------
__global__ __launch_bounds__(256) void gram_gemm(const __bf16* __restrict__ Eb, float* __restrict__ G) {
    __shared__ __bf16 As[128 * LDT] __attribute__((aligned(16)));
    __shared__ __bf16 Bs[128 * LDT] __attribute__((aligned(16)));
    int tid = threadIdx.x;
    int lane = tid & 63, wave = tid >> 6;
    // decode upper-triangle pair (by <= bx) from linear blockIdx over 300 blocks
    int by = 0, rem = blockIdx.x;
    while (rem >= NB128 - by) { rem -= (NB128 - by); ++by; }
    int bx = by + rem;
    size_t row0 = (size_t)by * 128, col0 = (size_t)bx * 128;
    int wr = wave >> 1, wc = wave & 1;          // wave -> 64x64 quadrant
    const f32x4 z4 = {0.f, 0.f, 0.f, 0.f};
    f32x4 acc[4][4];
    #pragma unroll
    for (int m = 0; m < 4; ++m)
        #pragma unroll
        for (int n = 0; n < 4; ++n) acc[m][n] = z4;

    int r_a = tid >> 2;          // staging row within [0,64)
    int c_a = (tid & 3) * 8;     // staging col 0/8/16/24
    const __bf16* arow = Eb + row0 * D_DIM;
    const __bf16* brow = Eb + col0 * D_DIM;
    int rl = lane & 15;
    int kg = (lane >> 4) * 8;    // k-offset of this lane's fragment

    for (int k0 = 0; k0 < D_DIM; k0 += 32) {
        bf16x8 a0 = *(const bf16x8*)(arow + (size_t)r_a * D_DIM + k0 + c_a);
        bf16x8 a1 = *(const bf16x8*)(arow + (size_t)(r_a + 64) * D_DIM + k0 + c_a);
        bf16x8 b0 = *(const bf16x8*)(brow + (size_t)r_a * D_DIM + k0 + c_a);
        bf16x8 b1 = *(const bf16x8*)(brow + (size_t)(r_a + 64) * D_DIM + k0 + c_a);
        __syncthreads();   // previous iteration's LDS reads done before overwrite
        *(bf16x8*)&As[r_a * LDT + c_a] = a0;
        *(bf16x8*)&As[(r_a + 64) * LDT + c_a] = a1;
        *(bf16x8*)&Bs[r_a * LDT + c_a] = b0;
        *(bf16x8*)&Bs[(r_a + 64) * LDT + c_a] = b1;
        __syncthreads();
        bf16x8 af[4], bf[4];
        #pragma unroll
        for (int m = 0; m < 4; ++m)
            af[m] = *(const bf16x8*)&As[(wr * 64 + m * 16 + rl) * LDT + kg];
        #pragma unroll
        for (int n = 0; n < 4; ++n)
            bf[n] = *(const bf16x8*)&Bs[(wc * 64 + n * 16 + rl) * LDT + kg];
        #pragma unroll
        for (int m = 0; m < 4; ++m)
            #pragma unroll
            for (int n = 0; n < 4; ++n)
                acc[m][n] = __builtin_amdgcn_mfma_f32_16x16x32_bf16(af[m], bf[n], acc[m][n], 0, 0, 0);
    }
    // C/D layout (HW-verified): col = lane&15, row = (lane>>4)*4 + reg
    int rg = (lane >> 4) * 4;
    #pragma unroll
    for (int m = 0; m < 4; ++m)
        #pragma unroll
        for (int n = 0; n < 4; ++n)
            #pragma unroll
            for (int r = 0; r < 4; ++r) {
                size_t row = row0 + wr * 64 + m * 16 + rg + r;
                size_t col = col0 + wc * 64 + n * 16 + rl;
                G[row * N_TOT + col] = acc[m][n][r];
            }
}

// ---------------- 3: mirror upper triangle into lower (64x64 LDS transpose tiles) ----------------
__global__ __launch_bounds__(256) void mirror_kernel(float* __restrict__ G) {
    __shared__ float s[64 * 65];
    int b = blockIdx.x;
    int p = b >> 2, q = b & 3;
    int bj = 0, rem = p;                       // 128-block pair, bi > bj
    while (rem >= NB128 - 1 - bj) { rem -= (NB128 - 1 - bj); ++bj; }
    int bi = bj + 1 + rem;
    int ti = bi * 2 + (q >> 1), tj = bj * 2 + (q & 1);   // 64-tile coords
    int tid = threadIdx.x;
    int c = tid & 63, r4 = tid >> 6;
    const float* src = G + ((size_t)tj * 64) * N_TOT + (size_t)ti * 64;  // upper tile (tj,ti)
    float* dst = G + ((size_t)ti * 64) * N_TOT + (size_t)tj * 64;        // lower tile (ti,tj)
    #pragma unroll
    for (int rr = 0; rr < 16; ++rr) {
        int row = rr * 4 + r4;
        s[row * 65 + c] = src[(size_t)row * N_TOT + c];
    }
    __syncthreads();
    #pragma unroll
    for (int rr = 0; rr < 16; ++rr) {
        int row = rr * 4 + r4;
        dst[(size_t)row * N_TOT + c] = s[c * 65 + row];   // stride-65 read: conflict-free
    }
}

// ---------------- 4: fused per-row T-binning + hard mining + successor term ----------------
// Grid = 3072 (one block per G row). Every row bins distances into its label's T row
// (64 LDS bins, 64 global atomics to flush — replaces the old tsum's 4096-bin pass and
// its 37.7 MB G re-read). Rows < B additionally do hard mining + the successor scan.
// Phase-2 scan now streams dneg as f32x4 broadcasts: 4x fewer LDS instructions (the
// R4 profile showed LDS-issue-bound scalar broadcasts, VALUBusy 23%).
__global__ __launch_bounds__(256) void rowtsum_kernel(
        const float* __restrict__ G, const float* __restrict__ norms,
        const int* __restrict__ albl, const int* __restrict__ nlbl,
        float* __restrict__ T, float* __restrict__ scal) {
    __shared__ float dneg[N_TOT] __attribute__((aligned(16)));  // negatives: dist; else BIG
    __shared__ float qlist[128];
    __shared__ float cpart[4 * 64];
    __shared__ float sred[256];
    __shared__ float tl[NCLS];
    __shared__ float acc2[2];
    __shared__ int pcount;
    int i = blockIdx.x, tid = threadIdx.x;
    int lane = tid & 63, wave = tid >> 6;
    bool mine = (i < B_DIM);                    // uniform per block
    if (tid == 0) { pcount = 0; acc2[0] = 0.f; acc2[1] = 0.f; }
    if (tid < NCLS) tl[tid] = 0.f;
    __syncthreads();
    int la = label_of(i, albl, nlbl);
    float ni = norms[i];
    const float* Grow = G + (size_t)i * N_TOT;
    float hp = -BIG_F, hn = BIG_F;
    for (int j = tid; j < N_TOT; j += 256) {
        float d2 = ni + norms[j] - 2.f * Grow[j];
        float dd = sqrtf(fmaxf(d2, 1e-8f));
        int lj = label_of(j, albl, nlbl);
        atomicAdd(&tl[lj], dd);                 // T-binning: row label fixed -> 64 bins
        if (mine) {
            bool isN = (lj != la);
            dneg[j] = isN ? dd : BIG_F;
            if (isN) {
                hn = fminf(hn, dd);
            } else if (j != i) {
                hp = fmaxf(hp, dd);
                int p = atomicAdd(&pcount, 1);
                if (p < 128) qlist[p] = dd;
            }
        }
    }
    __syncthreads();
    if (tid < NCLS) {
        float v = tl[tid];
        if (v != 0.f) atomicAdd(&T[la * NCLS + tid], v);
    }
    if (!mine) return;                          // uniform: whole block exits together

    float hpAll = block_reduce_max(hp, sred);
    float hnAll = block_reduce_min(hn, sred);   // barriers also publish dneg/qlist/pcount
    int P = min(pcount, 128);
    const int CH = N_TOT / 4;                   // 768 elements per wave
    for (int q0 = 0; q0 < P; q0 += 64) {
        int nq = min(64, P - q0);
        float q = (lane < nq) ? qlist[q0 + lane] : BIG_F;   // BIG sentinel: never matched
        float c0 = BIG_F, c1 = BIG_F, c2 = BIG_F, c3 = BIG_F;
        const f32x4* dv = (const f32x4*)&dneg[wave * CH];
        #pragma unroll 4
        for (int k = 0; k < CH / 4; ++k) {
            f32x4 v = dv[k];                    // 16B broadcast: 1 LDS instr / 4 elements
            c0 = fminf(c0, (v[0] > q) ? v[0] : BIG_F);
            c1 = fminf(c1, (v[1] > q) ? v[1] : BIG_F);
            c2 = fminf(c2, (v[2] > q) ? v[2] : BIG_F);
            c3 = fminf(c3, (v[3] > q) ? v[3] : BIG_F);
        }
        float c = fminf(fminf(c0, c1), fminf(c2, c3));
        cpart[wave * 64 + lane] = c;
        __syncthreads();
        if (wave == 0) {
            float cc = fminf(fminf(cpart[lane], cpart[64 + lane]),
                             fminf(cpart[128 + lane], cpart[192 + lane]));
            float s = 0.f, n = 0.f;
            if (lane < nq && cc < 1e29f) {
                float qq = qlist[q0 + lane];
                if (cc < qq + MARGIN_F) { s = qq - cc + MARGIN_F; n = 1.f; }
            }
            #pragma unroll
            for (int off = 32; off > 0; off >>= 1) {
                s += __shfl_down(s, off);
                n += __shfl_down(n, off);
            }
            if (lane == 0) { acc2[0] += s; acc2[1] += n; }
        }
        __syncthreads();
    }
    if (tid == 0) {
        if (P > 0 && hnAll < 1e29f) {
            atomicAdd(&scal[1], fmaxf(hpAll - hnAll + MARGIN_F, 0.f));
            atomicAdd(&scal[2], 1.f);
        }
        if (acc2[0] != 0.f || acc2[1] != 0.f) {
            atomicAdd(&scal[3], acc2[0]);
            atomicAdd(&scal[4], acc2[1]);
        }
    }
}

// ---------------- 5: finalize: counts, intra/inter, combine ----------------
__global__ __launch_bounds__(256) void finalize_kernel(
        const float* __restrict__ T, const int* __restrict__ albl, const int* __restrict__ nlbl,
        const float* __restrict__ scal, float* __restrict__ out) {
    __shared__ int counts[NCLS];
    __shared__ int inA[NCLS];
    __shared__ float sred[256];
    int tid = threadIdx.x;
    if (tid < NCLS) { counts[tid] = 0; inA[tid] = 0; }
    __syncthreads();
    for (int i = tid; i < B_DIM; i += 256) {
        atomicAdd(&counts[albl[i]], 2);   // anchor + positive share the label
        inA[albl[i]] = 1;
        atomicAdd(&counts[nlbl[i]], 1);
    }
    __syncthreads();
    float intra = 0.f;
    if (tid < NCLS) {
        int c = tid;
        float cnt = (float)counts[c];
        if (inA[c] && counts[c] > 1)
            intra = T[c * NCLS + c] / fmaxf(cnt * (cnt - 1.f), 1.f);
    }
    float inter = 0.f;
    for (int x = tid; x < NCLS * NCLS; x += 256) {
        int c1 = x >> 6, c2 = x & 63;
        if (c1 < c2 && inA[c1] && inA[c2]) {
            float pn = (float)counts[c1] * (float)counts[c2];
            if (pn > 0.f) inter += fmaxf(MARGIN_F - T[x] / fmaxf(pn, 1.f), 0.f);
        }
    }
    float intraAll = block_reduce_sum(intra, sred);
    float interAll = block_reduce_sum(inter, sred);
    if (tid == 0) {
        float trip = scal[0] / (float)B_DIM;
        float hard = (scal[2] > 0.f) ? scal[1] / fmaxf(scal[2], 1.f) : 0.f;
        float sh   = (scal[4] > 0.f) ? scal[3] / fmaxf(scal[4], 1.f) : 0.f;
        out[0] = trip + hard + sh + 0.1f * intraAll + 0.1f * interAll;
    }
}

// ---------------- launch ----------------
extern "C" void kernel_launch(void* const* d_in, const int* in_sizes, int n_in,
                              void* d_out, int out_size, void* d_ws, size_t ws_size,
                              hipStream_t stream) {
    const float* A  = (const float*)d_in[0];
    const float* P  = (const float*)d_in[1];
    const float* Ng = (const float*)d_in[2];
    const int* albl = (const int*)d_in[3];
    const int* nlbl = (const int*)d_in[4];
    char* ws = (char*)d_ws;
    // workspace layout (bytes)
    __bf16* Eb   = (__bf16*)(ws);                     // 3072*2048*2 = 12,582,912
    float* G     = (float*)(ws + 12582912);           // 3072*3072*4 = 37,748,736
    float* norms = (float*)(ws + 50331648);           // 3072*4
    float* T     = (float*)(ws + 50343936);           // 64*64*4
    float* scal  = (float*)(ws + 50360320);           // 8 floats
    float* out   = (float*)d_out;

    hipLaunchKernelGGL(zero_kernel, dim3(16), dim3(256), 0, stream, T, scal);
    hipLaunchKernelGGL(prep_kernel, dim3(B_DIM), dim3(256), 0, stream, A, P, Ng, Eb, norms, scal);
    hipLaunchKernelGGL(gram_gemm, dim3(NB128 * (NB128 + 1) / 2), dim3(256), 0, stream, Eb, G);
    hipLaunchKernelGGL(mirror_kernel, dim3((NB128 * (NB128 - 1) / 2) * 4), dim3(256), 0, stream, G);
    hipLaunchKernelGGL(rowtsum_kernel, dim3(N_TOT), dim3(256), 0, stream, G, norms, albl, nlbl, T, scal);
    hipLaunchKernelGGL(finalize_kernel, dim3(1), dim3(256), 0, stream, T, albl, nlbl, scal, out);
}